// Round 12
// baseline (4069.342 us; speedup 1.0000x reference)
//
#include <hip/hip_runtime.h>
#include <math.h>

// T=1000, B=256, F_IN=13 x3 -> 39 features, H=100, gates r,z,n (3H=300), 20 classes
#define T_STEPS 1000
#define BATCH   256
#define FIN     13
#define XDIM    39
#define HDIM    100
#define NCLS    20

#define NCONS   448     // 7 consumer waves: 8-lane group = 2 units, 16-col parts
#define NTHR    640     // + 3 producer waves (192 threads, 150 active) — R9 config
#define SLDS8   20      // part stride in floats (16 cols + 4 skew): banks 20p%32
                        // = {0,20,8,28,16,4,24,12} -> all 32 banks once -> conflict-free
#define HPAD8   160     // 8 parts * SLDS8

__device__ __forceinline__ float fast_sigmoid(float v) {
    return 1.f / (1.f + __expf(-v));
}
// DPP butterflies (pure VALU, no LDS pipe)
__device__ __forceinline__ float quad_xor1(float v) {
    return __int_as_float(__builtin_amdgcn_update_dpp(0, __float_as_int(v), 0xB1, 0xF, 0xF, true)); // [1,0,3,2]
}
__device__ __forceinline__ float quad_xor2(float v) {
    return __int_as_float(__builtin_amdgcn_update_dpp(0, __float_as_int(v), 0x4E, 0xF, 0xF, true)); // [2,3,0,1]
}
__device__ __forceinline__ float half_mir(float v) {   // lane ^ 7 within each 8 (row_half_mirror)
    return __int_as_float(__builtin_amdgcn_update_dpp(0, __float_as_int(v), 0x141, 0xF, 0xF, true));
}

// R10/R11 lesson: packed math (asm OR native) flips allocation to 64-VGPR mode
// and SLOWS DOWN while VALUBusy falls 84->56% -> issue count is NOT the bound.
// Revised model: the CU's LDS pipe is the serial resource (~12cy/b128 per wave-
// instruction); R9 spends ~1150cy/step on it vs 1790 measured. This round keeps
// R9's scalar math byte-for-byte where possible and cuts LDS wave-instructions:
//   consumers: 8-lane group = 2 adjacent units -> Vh 7 b128 -> 4 b128;
//              gi 3 b32 -> 3 b64 (flat gib, j0/j1 adjacent); h-write b32 -> b64.
//   3rd reduce level via DPP row_half_mirror (VALU, not ds_swizzle).
//   flat gib + float2 writes: bank conflicts 1.485e7 -> 0 (validated x3).
__attribute__((amdgpu_flat_work_group_size(NTHR, NTHR), amdgpu_waves_per_eu(2, 3)))
__global__ void gru_persistent(const float* __restrict__ mfcc0,
                               const float* __restrict__ mfcc1,
                               const float* __restrict__ mfcc2,
                               const float* __restrict__ len0,
                               const float* __restrict__ W_ih,
                               const float* __restrict__ W_hh,
                               const float* __restrict__ b_ih,
                               const float* __restrict__ b_hh,
                               const float* __restrict__ W_out,
                               const float* __restrict__ b_out,
                               float* __restrict__ out)
{
    const int b   = blockIdx.x;
    const int tid = threadIdx.x;

    __shared__ __align__(16) float Vh[2][HPAD8];      // h(t): part p at [20p..20p+15], skew pad
    __shared__ __align__(16) float gib[2][304];       // gi FLAT: [rr*100 + j]
    __shared__ __align__(16) float xbuf[2][40];       // x staging (39 + zero pad)
    __shared__ float feat[2 * HDIM];

    const bool isCons = (tid < NCONS);

    // ---- consumer geometry: 8-lane group G = units (2G, 2G+1), lane part p ----
    const int G  = tid >> 3;                    // 0..55 (consumers), active <50
    const int p  = tid & 7;                     // column part (16 cols at skewed base)
    const int Gc = (G < 50) ? G : 49;
    const int j0 = 2 * Gc;                      // even -> float2 alignment everywhere
    const int j1 = j0 + 1;

    // ---- producer geometry: rows (gA, gA+1) of the 300 gi rows ----
    const int q0 = isCons ? 0 : (tid - NCONS);  // 0..191, active <150
    const int gA = 2 * ((q0 < 150) ? q0 : 149);
    const int gB = gA + 1;

    // ---- SHARED weight registers: consumers w[0..23], producers w[0..19] ----
    float4 w[24];
    float  bA0 = 0.f, bA1 = 0.f, bA2 = 0.f;     // consumer: b_hh for j0; producer: b_ih pair
    float  bB0 = 0.f, bB1 = 0.f, bB2 = 0.f;     // consumer: b_hh for j1
    if (isCons) {
        const int base = 16 * p;
        #pragma unroll
        for (int rr = 0; rr < 3; ++rr) {
            const float* sA = W_hh + (rr * HDIM + j0) * HDIM;
            const float* sB = W_hh + (rr * HDIM + j1) * HDIM;
            #pragma unroll
            for (int i = 0; i < 4; ++i) {
                const int c = base + 4 * i;
                float4 tA, tB;
                tA.x = (c + 0 < HDIM) ? sA[c + 0] : 0.f;
                tA.y = (c + 1 < HDIM) ? sA[c + 1] : 0.f;
                tA.z = (c + 2 < HDIM) ? sA[c + 2] : 0.f;
                tA.w = (c + 3 < HDIM) ? sA[c + 3] : 0.f;
                tB.x = (c + 0 < HDIM) ? sB[c + 0] : 0.f;
                tB.y = (c + 1 < HDIM) ? sB[c + 1] : 0.f;
                tB.z = (c + 2 < HDIM) ? sB[c + 2] : 0.f;
                tB.w = (c + 3 < HDIM) ? sB[c + 3] : 0.f;
                w[rr * 4 + i]      = tA;
                w[12 + rr * 4 + i] = tB;
            }
        }
        bA0 = b_hh[j0]; bA1 = b_hh[HDIM + j0]; bA2 = b_hh[2 * HDIM + j0];
        bB0 = b_hh[j1]; bB1 = b_hh[HDIM + j1]; bB2 = b_hh[2 * HDIM + j1];
    } else {
        const float* sA = W_ih + gA * XDIM;
        const float* sB = W_ih + gB * XDIM;
        #pragma unroll
        for (int i = 0; i < 9; ++i) {
            w[i]      = make_float4(sA[4*i], sA[4*i+1], sA[4*i+2], sA[4*i+3]);
            w[10 + i] = make_float4(sB[4*i], sB[4*i+1], sB[4*i+2], sB[4*i+3]);
        }
        w[9]  = make_float4(sA[36], sA[37], sA[38], 0.f);   // pairs with xbuf[39]=0
        w[19] = make_float4(sB[36], sB[37], sB[38], 0.f);
        #pragma unroll
        for (int i = 20; i < 24; ++i) w[i] = make_float4(0, 0, 0, 0);
        bA0 = b_ih[gA]; bB0 = b_ih[gB];
    }

    // ---- producer x streaming source ----
    const float* xsrc = mfcc0;
    int xoff = b * FIN;
    if (!isCons && q0 < XDIM) {
        const int f = q0 % FIN;
        xsrc = (q0 < FIN) ? mfcc0 : (q0 < 2 * FIN ? mfcc1 : mfcc2);
        xoff = b * FIN + f;
    }

    // ---- prologue: h0 = 0 (both buffers incl. skew pads), stage x(0)/x(1), gi(0) ----
    if (tid < HPAD8) { Vh[0][tid] = 0.f; Vh[1][tid] = 0.f; }
    if (tid < 40) {
        float v0 = 0.f, v1 = 0.f;
        if (tid < XDIM) {
            const int f = tid % FIN;
            const float* xs = (tid < FIN) ? mfcc0 : (tid < 2 * FIN ? mfcc1 : mfcc2);
            v0 = xs[b * FIN + f];
            v1 = xs[(size_t)BATCH * FIN + b * FIN + f];
        }
        xbuf[0][tid] = v0; xbuf[1][tid] = v1;
    }
    __syncthreads();
    if (!isCons && q0 < 150) {
        const float4* X4 = (const float4*)xbuf[0];
        float a0=0,a1=0,a2=0,a3=0, c0=0,c1=0,c2=0,c3=0;
        #pragma unroll
        for (int i = 0; i < 10; ++i) {
            const float4 vv = X4[i];
            a0=fmaf(w[i].x,vv.x,a0);      a1=fmaf(w[i].y,vv.y,a1);
            a2=fmaf(w[i].z,vv.z,a2);      a3=fmaf(w[i].w,vv.w,a3);
            c0=fmaf(w[10+i].x,vv.x,c0);   c1=fmaf(w[10+i].y,vv.y,c1);
            c2=fmaf(w[10+i].z,vv.z,c2);   c3=fmaf(w[10+i].w,vv.w,c3);
        }
        *(float2*)&gib[0][gA] =
            make_float2(bA0 + ((a0+a1)+(a2+a3)), bB0 + ((c0+c1)+(c2+c3)));
    }
    __syncthreads();

    float hA = 0.f, hB = 0.f;         // h_j0, h_j1 replicated in all 8 group lanes
    float sumA = 0.f, sumB = 0.f, mxA = -INFINITY, mxB = -INFINITY;
    const int hdst = SLDS8 * (j0 >> 4) + (j0 & 15);   // j0/j1 cols (same part, adjacent)

    for (int t = 0; t < T_STEPS; ++t) {
        const int cur = t & 1;
        const int nxt = cur ^ 1;

        if (isCons) {
            // ---- gi reads first: 3 b64, flat layout, conflict-free, broadcast in-group ----
            const float2 gR = *(const float2*)&gib[cur][j0];
            const float2 gZ = *(const float2*)&gib[cur][HDIM + j0];
            const float2 gN = *(const float2*)&gib[cur][2 * HDIM + j0];
            // ---- GEMV: 4 b128 reads (skewed, conflict-free), 2 units x 3 gates x 16 cols ----
            const float4* V4 = (const float4*)(Vh[cur] + SLDS8 * p);
            float a00=0,a01=0,a10=0,a11=0,a20=0,a21=0;
            float c00=0,c01=0,c10=0,c11=0,c20=0,c21=0;
            #pragma unroll
            for (int i = 0; i < 4; ++i) {
                const float4 vv = V4[i];
                a00=fmaf(w[i].x,   vv.x,a00); a01=fmaf(w[i].y,   vv.y,a01);
                a00=fmaf(w[i].z,   vv.z,a00); a01=fmaf(w[i].w,   vv.w,a01);
                a10=fmaf(w[4+i].x, vv.x,a10); a11=fmaf(w[4+i].y, vv.y,a11);
                a10=fmaf(w[4+i].z, vv.z,a10); a11=fmaf(w[4+i].w, vv.w,a11);
                a20=fmaf(w[8+i].x, vv.x,a20); a21=fmaf(w[8+i].y, vv.y,a21);
                a20=fmaf(w[8+i].z, vv.z,a20); a21=fmaf(w[8+i].w, vv.w,a21);
                c00=fmaf(w[12+i].x,vv.x,c00); c01=fmaf(w[12+i].y,vv.y,c01);
                c00=fmaf(w[12+i].z,vv.z,c00); c01=fmaf(w[12+i].w,vv.w,c01);
                c10=fmaf(w[16+i].x,vv.x,c10); c11=fmaf(w[16+i].y,vv.y,c11);
                c10=fmaf(w[16+i].z,vv.z,c10); c11=fmaf(w[16+i].w,vv.w,c11);
                c20=fmaf(w[20+i].x,vv.x,c20); c21=fmaf(w[20+i].y,vv.y,c21);
                c20=fmaf(w[20+i].z,vv.z,c20); c21=fmaf(w[20+i].w,vv.w,c21);
            }
            float sA0 = a00+a01, sA1 = a10+a11, sA2 = a20+a21;
            float sB0 = c00+c01, sB1 = c10+c11, sB2 = c20+c21;
            // ---- 8-lane butterfly: xor1, xor2 (quad DPP) + lane^7 (row_half_mirror) ----
            sA0 += quad_xor1(sA0); sA1 += quad_xor1(sA1); sA2 += quad_xor1(sA2);
            sB0 += quad_xor1(sB0); sB1 += quad_xor1(sB1); sB2 += quad_xor1(sB2);
            sA0 += quad_xor2(sA0); sA1 += quad_xor2(sA1); sA2 += quad_xor2(sA2);
            sB0 += quad_xor2(sB0); sB1 += quad_xor2(sB1); sB2 += quad_xor2(sB2);
            sA0 += half_mir(sA0);  sA1 += half_mir(sA1);  sA2 += half_mir(sA2);
            sB0 += half_mir(sB0);  sB1 += half_mir(sB1);  sB2 += half_mir(sB2);
            // ---- gates + state update, fully in-register (both units, all 8 lanes) ----
            const float rA = fast_sigmoid(gR.x + sA0 + bA0);
            const float zA = fast_sigmoid(gZ.x + sA1 + bA1);
            const float nA = fmaf(2.f, fast_sigmoid(2.f * fmaf(rA, sA2 + bA2, gN.x)), -1.f);
            const float hvA = fmaf(zA, hA - nA, nA);       // (1-z)*n + z*h
            const float rB = fast_sigmoid(gR.y + sB0 + bB0);
            const float zB = fast_sigmoid(gZ.y + sB1 + bB1);
            const float nB = fmaf(2.f, fast_sigmoid(2.f * fmaf(rB, sB2 + bB2, gN.y)), -1.f);
            const float hvB = fmaf(zB, hB - nB, nB);
            hA = hvA; hB = hvB;
            sumA += hvA; mxA = fmaxf(mxA, hvA);
            sumB += hvB; mxB = fmaxf(mxB, hvB);
            if (p == 0 && G < 50)
                *(float2*)&Vh[nxt][hdst] = make_float2(hvA, hvB);  // publish h(t+1), b64
        } else {
            // ---- producers: prefetch x(t+2), compute gi(t+1) into gib[nxt] ----
            float xv = 0.f;
            const bool doX = (q0 < XDIM) && (t + 2 < T_STEPS);
            if (doX) xv = xsrc[(size_t)(t + 2) * (BATCH * FIN) + xoff];
            if ((t + 1 < T_STEPS) && q0 < 150) {
                const float4* X4 = (const float4*)xbuf[nxt];
                float a0=0,a1=0,a2=0,a3=0, c0=0,c1=0,c2=0,c3=0;
                #pragma unroll
                for (int i = 0; i < 10; ++i) {
                    const float4 vv = X4[i];
                    a0=fmaf(w[i].x,vv.x,a0);      a1=fmaf(w[i].y,vv.y,a1);
                    a2=fmaf(w[i].z,vv.z,a2);      a3=fmaf(w[i].w,vv.w,a3);
                    c0=fmaf(w[10+i].x,vv.x,c0);   c1=fmaf(w[10+i].y,vv.y,c1);
                    c2=fmaf(w[10+i].z,vv.z,c2);   c3=fmaf(w[10+i].w,vv.w,c3);
                }
                *(float2*)&gib[nxt][gA] =
                    make_float2(bA0 + ((a0+a1)+(a2+a3)), bB0 + ((c0+c1)+(c2+c3)));
            }
            if (doX) xbuf[cur][q0] = xv;
        }
        __syncthreads();
    }

    // ---- pooling + output linear ----
    if (isCons && p == 0 && G < 50) {
        const float il = 1.f / len0[b];
        feat[j0]        = sumA * il;
        feat[j1]        = sumB * il;
        feat[HDIM + j0] = mxA;
        feat[HDIM + j1] = mxB;
    }
    __syncthreads();

    if (tid < NCLS) {
        float acc = b_out[tid];
        #pragma unroll 4
        for (int k = 0; k < 2 * HDIM; ++k)
            acc = fmaf(W_out[tid * 2 * HDIM + k], feat[k], acc);
        out[b * NCLS + tid] = acc;
    }
}

extern "C" void kernel_launch(void* const* d_in, const int* in_sizes, int n_in,
                              void* d_out, int out_size, void* d_ws, size_t ws_size,
                              hipStream_t stream)
{
    const float* mfcc0 = (const float*)d_in[0];
    const float* mfcc1 = (const float*)d_in[1];
    const float* mfcc2 = (const float*)d_in[2];
    const float* len0  = (const float*)d_in[3];
    const float* W_ih  = (const float*)d_in[4];
    const float* W_hh  = (const float*)d_in[5];
    const float* b_ih  = (const float*)d_in[6];
    const float* b_hh  = (const float*)d_in[7];
    const float* W_out = (const float*)d_in[8];
    const float* b_out = (const float*)d_in[9];
    float* out = (float*)d_out;

    gru_persistent<<<BATCH, NTHR, 0, stream>>>(
        mfcc0, mfcc1, mfcc2, len0, W_ih, W_hh, b_ih, b_hh, W_out, b_out, out);
}

// Round 13
// 737.322 us; speedup vs baseline: 5.5191x; 5.5191x over previous
//
#include <hip/hip_runtime.h>
#include <math.h>

// T=1000, B=256, F_IN=13 x3 -> 39 features, H=100, gates r,z,n (3H=300), 20 classes
#define T_STEPS 1000
#define BATCH   256
#define FIN     13
#define XDIM    39
#define HDIM    100
#define NCLS    20
#define GI3     300

__device__ __forceinline__ float fast_sigmoid(float v) {
    return 1.f / (1.f + __expf(-v));
}
// DPP butterflies (pure VALU, no LDS pipe). All validated R9/R12 (passed).
__device__ __forceinline__ float quad_xor1(float v) {
    return __int_as_float(__builtin_amdgcn_update_dpp(0, __float_as_int(v), 0xB1, 0xF, 0xF, true)); // [1,0,3,2]
}
__device__ __forceinline__ float quad_xor2(float v) {
    return __int_as_float(__builtin_amdgcn_update_dpp(0, __float_as_int(v), 0x4E, 0xF, 0xF, true)); // [2,3,0,1]
}
__device__ __forceinline__ float half_mir(float v) {   // lane ^ 7 within each 8 (row_half_mirror)
    return __int_as_float(__builtin_amdgcn_update_dpp(0, __float_as_int(v), 0x141, 0xF, 0xF, true));
}

// ============================================================================
// Kernel 1: gi[b][t][g] = b_ih[g] + W_ih[g,:] @ x[t,b,:]  (no h dependence).
// 2048 blocks (b x 8 t-chunks) x 320 threads; writes coalesced (thread g -> +g).
// ============================================================================
__launch_bounds__(320)
__global__ void gi_prepass(const float* __restrict__ mfcc0,
                           const float* __restrict__ mfcc1,
                           const float* __restrict__ mfcc2,
                           const float* __restrict__ W_ih,
                           const float* __restrict__ b_ih,
                           float* __restrict__ gi)
{
    const int b  = blockIdx.x;
    const int tc = blockIdx.y;            // 0..7 -> 125 steps each
    const int g  = threadIdx.x;           // 0..319, active <300

    __shared__ __align__(16) float xs[40];

    float4 w[10];
    float  bias = 0.f;
    if (g < GI3) {
        const float* src = W_ih + g * XDIM;
        #pragma unroll
        for (int i = 0; i < 9; ++i)
            w[i] = make_float4(src[4*i], src[4*i+1], src[4*i+2], src[4*i+3]);
        w[9] = make_float4(src[36], src[37], src[38], 0.f);   // pairs with xs[39]=0
        bias = b_ih[g];
    }

    const int t0 = tc * 125;
    for (int t = t0; t < t0 + 125; ++t) {
        __syncthreads();                  // protect xs from previous-iter readers
        if (threadIdx.x < 40) {
            float v = 0.f;
            if (threadIdx.x < XDIM) {
                const int f = threadIdx.x % FIN;
                const float* xsrc = (threadIdx.x < FIN) ? mfcc0
                                  : (threadIdx.x < 2 * FIN ? mfcc1 : mfcc2);
                v = xsrc[((size_t)t * BATCH + b) * FIN + f];
            }
            xs[threadIdx.x] = v;
        }
        __syncthreads();
        if (g < GI3) {
            const float4* X4 = (const float4*)xs;
            float a0 = 0.f, a1 = 0.f, a2 = 0.f, a3 = 0.f;
            #pragma unroll
            for (int i = 0; i < 10; ++i) {
                const float4 vv = X4[i];
                a0 = fmaf(w[i].x, vv.x, a0); a1 = fmaf(w[i].y, vv.y, a1);
                a2 = fmaf(w[i].z, vv.z, a2); a3 = fmaf(w[i].w, vv.w, a3);
            }
            gi[((size_t)b * T_STEPS + t) * GI3 + g] = bias + ((a0 + a1) + (a2 + a3));
        }
    }
}

// ============================================================================
// Kernel 2: consumer-only persistent GRU. B=512 (the R2-proven 128-VGPR
// contract; held 104 weight floats with zero scratch). 8-lane group = 2 units
// (R12's correctness-validated mapping, 96 weight floats), 16 cols/lane at
// skewed stride-20 bases (conflict-free, measured 0 in R12). gi comes from
// global via 1-step-ahead float2 prefetch (latency hidden under the GEMV).
// LDS traffic/step: ~26 KB (vs R9's ~80 KB) and zero producer waves.
// ============================================================================
#define LNTHR   512
#define SLDS8   20
#define HPAD8   160

__launch_bounds__(LNTHR, 2)
__global__ void gru_loop(const float* __restrict__ len0,
                         const float* __restrict__ W_hh,
                         const float* __restrict__ b_hh,
                         const float* __restrict__ W_out,
                         const float* __restrict__ b_out,
                         const float* __restrict__ gi,
                         float* __restrict__ out)
{
    const int b   = blockIdx.x;
    const int tid = threadIdx.x;

    __shared__ __align__(16) float Vh[2][HPAD8];  // h(t): part p at [20p..20p+15], skew pad
    __shared__ float feat[2 * HDIM];

    // ---- geometry: 8-lane group G = units (2G, 2G+1), lane part p ----
    const int G  = tid >> 3;                  // 0..63, active <50
    const int p  = tid & 7;
    const int Gc = (G < 50) ? G : 49;
    const int j0 = 2 * Gc;                    // even -> float2-aligned everywhere
    const int j1 = j0 + 1;

    // ---- weights: 2 units x 3 gates x 16 cols = 24 float4 (96 floats) ----
    float4 w[24];
    {
        const int base = 16 * p;
        #pragma unroll
        for (int rr = 0; rr < 3; ++rr) {
            const float* sA = W_hh + (rr * HDIM + j0) * HDIM;
            const float* sB = W_hh + (rr * HDIM + j1) * HDIM;
            #pragma unroll
            for (int i = 0; i < 4; ++i) {
                const int c = base + 4 * i;
                float4 tA, tB;
                tA.x = (c + 0 < HDIM) ? sA[c + 0] : 0.f;
                tA.y = (c + 1 < HDIM) ? sA[c + 1] : 0.f;
                tA.z = (c + 2 < HDIM) ? sA[c + 2] : 0.f;
                tA.w = (c + 3 < HDIM) ? sA[c + 3] : 0.f;
                tB.x = (c + 0 < HDIM) ? sB[c + 0] : 0.f;
                tB.y = (c + 1 < HDIM) ? sB[c + 1] : 0.f;
                tB.z = (c + 2 < HDIM) ? sB[c + 2] : 0.f;
                tB.w = (c + 3 < HDIM) ? sB[c + 3] : 0.f;
                w[rr * 4 + i]      = tA;
                w[12 + rr * 4 + i] = tB;
            }
        }
    }
    const float bA0 = b_hh[j0], bA1 = b_hh[HDIM + j0], bA2 = b_hh[2 * HDIM + j0];
    const float bB0 = b_hh[j1], bB1 = b_hh[HDIM + j1], bB2 = b_hh[2 * HDIM + j1];

    // ---- prologue: zero both Vh buffers (incl. skew pads); load gi row t=0 ----
    if (tid < HPAD8) { Vh[0][tid] = 0.f; Vh[1][tid] = 0.f; }
    const float* gbase = gi + (size_t)b * T_STEPS * GI3;
    float2 gR = *(const float2*)(gbase + j0);
    float2 gZ = *(const float2*)(gbase + HDIM + j0);
    float2 gN = *(const float2*)(gbase + 2 * HDIM + j0);
    __syncthreads();

    float hA = 0.f, hB = 0.f;
    float sumA = 0.f, sumB = 0.f, mxA = -INFINITY, mxB = -INFINITY;
    const int hdst = SLDS8 * (j0 >> 4) + (j0 & 15);

    for (int t = 0; t < T_STEPS; ++t) {
        const int cur = t & 1;
        const int nxt = cur ^ 1;

        // ---- prefetch gi row t+1 (global, quad-uniform -> L1 broadcast) ----
        const float* nrow = gbase + (size_t)((t + 1 < T_STEPS) ? t + 1 : t) * GI3;
        const float2 nR = *(const float2*)(nrow + j0);
        const float2 nZ = *(const float2*)(nrow + HDIM + j0);
        const float2 nN = *(const float2*)(nrow + 2 * HDIM + j0);

        // ---- GEMV: 4 b128 reads (skewed, conflict-free), 2 units x 3 gates ----
        const float4* V4 = (const float4*)(Vh[cur] + SLDS8 * p);
        float a00=0,a01=0,a10=0,a11=0,a20=0,a21=0;
        float c00=0,c01=0,c10=0,c11=0,c20=0,c21=0;
        #pragma unroll
        for (int i = 0; i < 4; ++i) {
            const float4 vv = V4[i];
            a00=fmaf(w[i].x,   vv.x,a00); a01=fmaf(w[i].y,   vv.y,a01);
            a00=fmaf(w[i].z,   vv.z,a00); a01=fmaf(w[i].w,   vv.w,a01);
            a10=fmaf(w[4+i].x, vv.x,a10); a11=fmaf(w[4+i].y, vv.y,a11);
            a10=fmaf(w[4+i].z, vv.z,a10); a11=fmaf(w[4+i].w, vv.w,a11);
            a20=fmaf(w[8+i].x, vv.x,a20); a21=fmaf(w[8+i].y, vv.y,a21);
            a20=fmaf(w[8+i].z, vv.z,a20); a21=fmaf(w[8+i].w, vv.w,a21);
            c00=fmaf(w[12+i].x,vv.x,c00); c01=fmaf(w[12+i].y,vv.y,c01);
            c00=fmaf(w[12+i].z,vv.z,c00); c01=fmaf(w[12+i].w,vv.w,c01);
            c10=fmaf(w[16+i].x,vv.x,c10); c11=fmaf(w[16+i].y,vv.y,c11);
            c10=fmaf(w[16+i].z,vv.z,c10); c11=fmaf(w[16+i].w,vv.w,c11);
            c20=fmaf(w[20+i].x,vv.x,c20); c21=fmaf(w[20+i].y,vv.y,c21);
            c20=fmaf(w[20+i].z,vv.z,c20); c21=fmaf(w[20+i].w,vv.w,c21);
        }
        float sA0 = a00+a01, sA1 = a10+a11, sA2 = a20+a21;
        float sB0 = c00+c01, sB1 = c10+c11, sB2 = c20+c21;
        // ---- 8-lane butterfly: xor1, xor2 (quad DPP) + lane^7 (half mirror) ----
        sA0 += quad_xor1(sA0); sA1 += quad_xor1(sA1); sA2 += quad_xor1(sA2);
        sB0 += quad_xor1(sB0); sB1 += quad_xor1(sB1); sB2 += quad_xor1(sB2);
        sA0 += quad_xor2(sA0); sA1 += quad_xor2(sA1); sA2 += quad_xor2(sA2);
        sB0 += quad_xor2(sB0); sB1 += quad_xor2(sB1); sB2 += quad_xor2(sB2);
        sA0 += half_mir(sA0);  sA1 += half_mir(sA1);  sA2 += half_mir(sA2);
        sB0 += half_mir(sB0);  sB1 += half_mir(sB1);  sB2 += half_mir(sB2);
        // ---- gates + state update, fully in-register (both units, all 8 lanes) ----
        const float rA = fast_sigmoid(gR.x + sA0 + bA0);
        const float zA = fast_sigmoid(gZ.x + sA1 + bA1);
        const float nA = fmaf(2.f, fast_sigmoid(2.f * fmaf(rA, sA2 + bA2, gN.x)), -1.f);
        const float hvA = fmaf(zA, hA - nA, nA);          // (1-z)*n + z*h
        const float rB = fast_sigmoid(gR.y + sB0 + bB0);
        const float zB = fast_sigmoid(gZ.y + sB1 + bB1);
        const float nB = fmaf(2.f, fast_sigmoid(2.f * fmaf(rB, sB2 + bB2, gN.y)), -1.f);
        const float hvB = fmaf(zB, hB - nB, nB);
        hA = hvA; hB = hvB;
        sumA += hvA; mxA = fmaxf(mxA, hvA);
        sumB += hvB; mxB = fmaxf(mxB, hvB);
        if (p == 0 && G < 50)
            *(float2*)&Vh[nxt][hdst] = make_float2(hvA, hvB);   // publish h(t+1)
        gR = nR; gZ = nZ; gN = nN;
        __syncthreads();
    }

    // ---- pooling + output linear ----
    if (p == 0 && G < 50) {
        const float il = 1.f / len0[b];
        feat[j0]        = sumA * il;
        feat[j1]        = sumB * il;
        feat[HDIM + j0] = mxA;
        feat[HDIM + j1] = mxB;
    }
    __syncthreads();

    if (tid < NCLS) {
        float acc = b_out[tid];
        #pragma unroll 4
        for (int k = 0; k < 2 * HDIM; ++k)
            acc = fmaf(W_out[tid * 2 * HDIM + k], feat[k], acc);
        out[b * NCLS + tid] = acc;
    }
}

// ============================================================================
// Fallback: R9 kernel verbatim (735 us proven) — used when ws_size < 307 MB.
// ============================================================================
#define NCONS   448
#define NTHR    640
#define HPAD    112
#define PCOLS   28

__attribute__((amdgpu_flat_work_group_size(NTHR, NTHR), amdgpu_waves_per_eu(2, 3)))
__global__ void gru_persistent(const float* __restrict__ mfcc0,
                               const float* __restrict__ mfcc1,
                               const float* __restrict__ mfcc2,
                               const float* __restrict__ len0,
                               const float* __restrict__ W_ih,
                               const float* __restrict__ W_hh,
                               const float* __restrict__ b_ih,
                               const float* __restrict__ b_hh,
                               const float* __restrict__ W_out,
                               const float* __restrict__ b_out,
                               float* __restrict__ out)
{
    const int b   = blockIdx.x;
    const int tid = threadIdx.x;

    __shared__ __align__(16) float Vh[2][HPAD];
    __shared__ __align__(16) float gib[2][4 * HDIM];
    __shared__ __align__(16) float xbuf[2][40];
    __shared__ float feat[2 * HDIM];

    const bool isCons = (tid < NCONS);
    const int q  = tid >> 2;
    const int p  = tid & 3;
    const int j  = (q < HDIM) ? q : (HDIM - 1);
    const int q0 = isCons ? 0 : (tid - NCONS);
    const int gA = 2 * ((q0 < 150) ? q0 : 149);
    const int gB = gA + 1;

    float4 w[21];
    float  bh0 = 0.f, bh1 = 0.f, bh2 = 0.f;
    int    ofA = 0, ofB = 0;
    if (isCons) {
        const int base = PCOLS * p;
        #pragma unroll
        for (int rr = 0; rr < 3; ++rr) {
            const float* src = W_hh + (rr * HDIM + j) * HDIM;
            #pragma unroll
            for (int i = 0; i < 7; ++i) {
                const int c = base + 4 * i;
                float4 t;
                t.x = (c + 0 < HDIM) ? src[c + 0] : 0.f;
                t.y = (c + 1 < HDIM) ? src[c + 1] : 0.f;
                t.z = (c + 2 < HDIM) ? src[c + 2] : 0.f;
                t.w = (c + 3 < HDIM) ? src[c + 3] : 0.f;
                w[rr * 7 + i] = t;
            }
        }
        bh0 = b_hh[j]; bh1 = b_hh[HDIM + j]; bh2 = b_hh[2 * HDIM + j];
    } else {
        const float* sA = W_ih + gA * XDIM;
        const float* sB = W_ih + gB * XDIM;
        #pragma unroll
        for (int i = 0; i < 9; ++i) {
            w[i]      = make_float4(sA[4*i], sA[4*i+1], sA[4*i+2], sA[4*i+3]);
            w[10 + i] = make_float4(sB[4*i], sB[4*i+1], sB[4*i+2], sB[4*i+3]);
        }
        w[9]  = make_float4(sA[36], sA[37], sA[38], 0.f);
        w[19] = make_float4(sB[36], sB[37], sB[38], 0.f);
        w[20] = make_float4(0, 0, 0, 0);
        bh0 = b_ih[gA]; bh1 = b_ih[gB];
        ofA = (gA % HDIM) * 4 + gA / HDIM;
        ofB = (gB % HDIM) * 4 + gB / HDIM;
    }

    const float* xsrc = mfcc0;
    int xoff = b * FIN;
    if (!isCons && q0 < XDIM) {
        const int f = q0 % FIN;
        xsrc = (q0 < FIN) ? mfcc0 : (q0 < 2 * FIN ? mfcc1 : mfcc2);
        xoff = b * FIN + f;
    }

    if (tid < HPAD) { Vh[0][tid] = 0.f; Vh[1][tid] = 0.f; }
    if (tid < 40) {
        float v0 = 0.f, v1 = 0.f;
        if (tid < XDIM) {
            const int f = tid % FIN;
            const float* xs = (tid < FIN) ? mfcc0 : (tid < 2 * FIN ? mfcc1 : mfcc2);
            v0 = xs[b * FIN + f];
            v1 = xs[(size_t)BATCH * FIN + b * FIN + f];
        }
        xbuf[0][tid] = v0; xbuf[1][tid] = v1;
    }
    __syncthreads();
    if (!isCons && q0 < 150) {
        const float4* X4 = (const float4*)xbuf[0];
        float a0=0,a1=0,a2=0,a3=0, c0=0,c1=0,c2=0,c3=0;
        #pragma unroll
        for (int i = 0; i < 10; ++i) {
            const float4 vv = X4[i];
            a0=fmaf(w[i].x,vv.x,a0);      a1=fmaf(w[i].y,vv.y,a1);
            a2=fmaf(w[i].z,vv.z,a2);      a3=fmaf(w[i].w,vv.w,a3);
            c0=fmaf(w[10+i].x,vv.x,c0);   c1=fmaf(w[10+i].y,vv.y,c1);
            c2=fmaf(w[10+i].z,vv.z,c2);   c3=fmaf(w[10+i].w,vv.w,c3);
        }
        gib[0][ofA] = bh0 + ((a0+a1)+(a2+a3));
        gib[0][ofB] = bh1 + ((c0+c1)+(c2+c3));
    }
    __syncthreads();

    float hreg = 0.f;
    float sum = 0.f, mx = -INFINITY;

    for (int t = 0; t < T_STEPS; ++t) {
        const int cur = t & 1;
        const int nxt = cur ^ 1;

        if (isCons) {
            const float4 g4 = ((const float4*)gib[cur])[j];
            const float4* V4 = (const float4*)(Vh[cur] + p * PCOLS);
            float a0=0,a1=0,a2=0,a3=0, b0=0,b1=0,b2=0,b3=0, c0=0,c1=0,c2=0,c3=0;
            #pragma unroll
            for (int i = 0; i < 7; ++i) {
                const float4 vv = V4[i];
                a0=fmaf(w[i].x,vv.x,a0);      a1=fmaf(w[i].y,vv.y,a1);
                a2=fmaf(w[i].z,vv.z,a2);      a3=fmaf(w[i].w,vv.w,a3);
                b0=fmaf(w[7+i].x,vv.x,b0);    b1=fmaf(w[7+i].y,vv.y,b1);
                b2=fmaf(w[7+i].z,vv.z,b2);    b3=fmaf(w[7+i].w,vv.w,b3);
                c0=fmaf(w[14+i].x,vv.x,c0);   c1=fmaf(w[14+i].y,vv.y,c1);
                c2=fmaf(w[14+i].z,vv.z,c2);   c3=fmaf(w[14+i].w,vv.w,c3);
            }
            float s0 = (a0+a1)+(a2+a3);
            float s1 = (b0+b1)+(b2+b3);
            float s2 = (c0+c1)+(c2+c3);
            s0 += quad_xor1(s0); s1 += quad_xor1(s1); s2 += quad_xor1(s2);
            s0 += quad_xor2(s0); s1 += quad_xor2(s1); s2 += quad_xor2(s2);
            const float rg = fast_sigmoid(g4.x + s0 + bh0);
            const float zg = fast_sigmoid(g4.y + s1 + bh1);
            const float na = fmaf(rg, s2 + bh2, g4.z);
            const float ng = fmaf(2.f, fast_sigmoid(2.f * na), -1.f);
            const float hv = fmaf(zg, hreg - ng, ng);
            hreg = hv;
            sum += hv; mx = fmaxf(mx, hv);
            if (p == 0 && q < HDIM) Vh[nxt][q] = hv;
        } else {
            float xv = 0.f;
            const bool doX = (q0 < XDIM) && (t + 2 < T_STEPS);
            if (doX) xv = xsrc[(size_t)(t + 2) * (BATCH * FIN) + xoff];
            if ((t + 1 < T_STEPS) && q0 < 150) {
                const float4* X4 = (const float4*)xbuf[nxt];
                float a0=0,a1=0,a2=0,a3=0, c0=0,c1=0,c2=0,c3=0;
                #pragma unroll
                for (int i = 0; i < 10; ++i) {
                    const float4 vv = X4[i];
                    a0=fmaf(w[i].x,vv.x,a0);      a1=fmaf(w[i].y,vv.y,a1);
                    a2=fmaf(w[i].z,vv.z,a2);      a3=fmaf(w[i].w,vv.w,a3);
                    c0=fmaf(w[10+i].x,vv.x,c0);   c1=fmaf(w[10+i].y,vv.y,c1);
                    c2=fmaf(w[10+i].z,vv.z,c2);   c3=fmaf(w[10+i].w,vv.w,c3);
                }
                gib[nxt][ofA] = bh0 + ((a0+a1)+(a2+a3));
                gib[nxt][ofB] = bh1 + ((c0+c1)+(c2+c3));
            }
            if (doX) xbuf[cur][q0] = xv;
        }
        __syncthreads();
    }

    if (isCons && p == 0 && q < HDIM) {
        feat[q]        = sum / len0[b];
        feat[HDIM + q] = mx;
    }
    __syncthreads();

    if (tid < NCLS) {
        float acc = b_out[tid];
        #pragma unroll 4
        for (int k = 0; k < 2 * HDIM; ++k)
            acc = fmaf(W_out[tid * 2 * HDIM + k], feat[k], acc);
        out[b * NCLS + tid] = acc;
    }
}

extern "C" void kernel_launch(void* const* d_in, const int* in_sizes, int n_in,
                              void* d_out, int out_size, void* d_ws, size_t ws_size,
                              hipStream_t stream)
{
    const float* mfcc0 = (const float*)d_in[0];
    const float* mfcc1 = (const float*)d_in[1];
    const float* mfcc2 = (const float*)d_in[2];
    const float* len0  = (const float*)d_in[3];
    const float* W_ih  = (const float*)d_in[4];
    const float* W_hh  = (const float*)d_in[5];
    const float* b_ih  = (const float*)d_in[6];
    const float* b_hh  = (const float*)d_in[7];
    const float* W_out = (const float*)d_in[8];
    const float* b_out = (const float*)d_in[9];
    float* out = (float*)d_out;

    const size_t need = (size_t)BATCH * T_STEPS * GI3 * sizeof(float);  // 307.2 MB
    if (d_ws != nullptr && ws_size >= need) {
        dim3 g1(BATCH, 8);
        gi_prepass<<<g1, 320, 0, stream>>>(mfcc0, mfcc1, mfcc2, W_ih, b_ih, (float*)d_ws);
        gru_loop<<<BATCH, LNTHR, 0, stream>>>(len0, W_hh, b_hh, W_out, b_out,
                                              (const float*)d_ws, out);
    } else {
        gru_persistent<<<BATCH, NTHR, 0, stream>>>(
            mfcc0, mfcc1, mfcc2, len0, W_ih, W_hh, b_ih, b_hh, W_out, b_out, out);
    }
}